// Round 3
// baseline (77.975 us; speedup 1.0000x reference)
//
#include <hip/hip_runtime.h>
#include <math.h>

// Problem constants (fixed by setup_inputs):
//   k_b=4, c_out=64, c_in=8, N=4096, m=8, ker=N/(2m)=256, c=2*pi*m/N
// Analytic collapse (R0 journal), plus exact identities Gi==Hr, Hi==-Gr
// (the bilinear forms are term-by-term identical), so per (b,o):
//   Gr = sum_{i,t} zr*(-P c + Q s) + zi*(Q c + P s)
//   Hr = sum_{i,t} zr*(-P s - Q c) + zi*(-P c + Q s)
//   sr(mu) = -(cos(c mu) Gr + sin(c mu) Hr)
//   si(mu) =  sin(c mu) Gr - cos(c mu) Hr
// Reorganized with per-t partials X = sum_i(-P zr + Q zi), Y = sum_i(Q zr + P zi):
//   Gr += c X + s Y ;  Hr += s X - c Y
// All angles are exact multiples of (r/4096) revolutions -> HW v_sin/v_cos.
// Single fused kernel: each (b,o) block re-reduces its batch's 256 KB
// (L2-resident; 67 MB aggregate cache reads ~ 2 us) -> no workspace, 1 launch.

#define KB   4
#define COUT 64
#define CIN  8
#define NN   4096
#define INV_N   (1.0f / 4096.0f)
#define INV_2PI 0.15915494309189535f

__global__ __launch_bounds__(256) void capa_fused_kernel(
    const float* __restrict__ zr,
    const float* __restrict__ zi,
    const float* __restrict__ A,
    const float* __restrict__ beta,
    const float* __restrict__ bias,
    const int*   __restrict__ m_ptr,
    float* __restrict__ out) {

    const int blk = blockIdx.x;             // b*COUT + o
    const int b = blk >> 6, o = blk & (COUT - 1);
    const int m = *m_ptr;
    const int tid = threadIdx.x;

    // per-i mixing coefficients P = |A|cos(beta), Q = |A|sin(beta)
    float P[CIN], Q[CIN];
    #pragma unroll
    for (int i = 0; i < CIN; ++i) {
        float a  = fabsf(A[o * CIN + i]);
        float rb = beta[o * CIN + i] * INV_2PI;   // radians -> revolutions
        P[i] = a * __builtin_amdgcn_cosf(rb);
        Q[i] = a * __builtin_amdgcn_sinf(rb);
    }

    // ---- phase 1: reduce Gr, Hr over this block's batch (8 x 4096 x 2 floats)
    const float4* xr = (const float4*)(zr + b * CIN * NN);
    const float4* xi = (const float4*)(zi + b * CIN * NN);

    float gr = 0.f, hr = 0.f;
    #pragma unroll
    for (int k = 0; k < NN / 4 / 256; ++k) {        // 4 iters
        int vidx = tid + k * 256;                   // float4 index in a row (1024/row)
        float4 vr[CIN], vi[CIN];
        #pragma unroll
        for (int i = 0; i < CIN; ++i) {
            vr[i] = xr[i * (NN / 4) + vidx];
            vi[i] = xi[i * (NN / 4) + vidx];
        }
        int t0 = vidx * 4;
        #pragma unroll
        for (int j = 0; j < 4; ++j) {
            float X = 0.f, Y = 0.f;
            #pragma unroll
            for (int i = 0; i < CIN; ++i) {
                float a = (&vr[i].x)[j];
                float c2 = (&vi[i].x)[j];
                X += -P[i] * a + Q[i] * c2;
                Y +=  Q[i] * a + P[i] * c2;
            }
            int r = (m * (t0 + j)) & (NN - 1);      // exact phase mod 1 rev
            float rev = (float)r * INV_N;
            float s = __builtin_amdgcn_sinf(rev);
            float c = __builtin_amdgcn_cosf(rev);
            gr += c * X + s * Y;
            hr += s * X - c * Y;
        }
    }

    // block reduction: wave64 shuffle, then LDS across 4 waves
    #pragma unroll
    for (int off = 32; off > 0; off >>= 1) {
        gr += __shfl_down(gr, off);
        hr += __shfl_down(hr, off);
    }
    __shared__ float red[4][2];
    int wave = tid >> 6, lane = tid & 63;
    if (lane == 0) { red[wave][0] = gr; red[wave][1] = hr; }
    __syncthreads();
    const float Gr = red[0][0] + red[1][0] + red[2][0] + red[3][0];
    const float Hr = red[0][1] + red[1][1] + red[2][1] + red[3][1];

    // ---- phase 2: write 4096 (sr, si) pairs for this (b,o)
    const float bo = bias[o];
    float4* out_r = (float4*)(out + ((long)blk << 12));
    float4* out_i = (float4*)(out + (long)KB * COUT * NN + ((long)blk << 12));

    #pragma unroll
    for (int k = 0; k < NN / 4 / 256; ++k) {
        int vidx = tid + k * 256;
        int mu0 = vidx * 4;
        float4 o1, o2;
        #pragma unroll
        for (int j = 0; j < 4; ++j) {
            int r = (m * (mu0 + j)) & (NN - 1);
            float rev = (float)r * INV_N;
            float s = __builtin_amdgcn_sinf(rev);
            float c = __builtin_amdgcn_cosf(rev);
            float sr = -(c * Gr + s * Hr);
            float si = s * Gr - c * Hr;
            float mag = sqrtf(sr * sr + si * si);
            float gate = 1.0f / ((1.0f + __expf(-(mag + bo))) * (mag + 1e-5f));
            (&o1.x)[j] = gate * sr;
            (&o2.x)[j] = gate * si;
        }
        out_r[vidx] = o1;
        out_i[vidx] = o2;
    }
}

extern "C" void kernel_launch(void* const* d_in, const int* in_sizes, int n_in,
                              void* d_out, int out_size, void* d_ws, size_t ws_size,
                              hipStream_t stream) {
    const float* z_real = (const float*)d_in[0];
    const float* z_imag = (const float*)d_in[1];
    const float* A      = (const float*)d_in[2];
    const float* beta   = (const float*)d_in[3];
    const float* bias   = (const float*)d_in[4];
    const int*   m_ptr  = (const int*)d_in[5];
    float* out = (float*)d_out;

    capa_fused_kernel<<<KB * COUT, 256, 0, stream>>>(
        z_real, z_imag, A, beta, bias, m_ptr, out);
}

// Round 4
// 71.593 us; speedup vs baseline: 1.0891x; 1.0891x over previous
//
#include <hip/hip_runtime.h>
#include <math.h>

// Problem constants (fixed by setup_inputs):
//   k_b=4, c_out=64, c_in=8, N=4096, m=8, ker=N/(2m)=256, c=2*pi*m/N
// Analytic collapse (R0 journal):
//   per (b,i): Fcr=sum_t zr cos(ct), Fsr=sum_t zr sin(ct), Fci/Fsi likewise for zi
//   per (b,o): Gr = sum_i(-P Fcr + Q Fsr + Q Fci + P Fsi)
//              Hr = sum_i(-P Fsr - Q Fcr + Q Fsi - P Fci)   [P=|A|cos b, Q=|A|sin b]
//   exact identities Gi==Hr, Hi==-Gr  (verified R3) =>
//   sr(mu) = -(c Gr + s Hr);  si(mu) = s Gr - c Hr   [c,s at angle c*mu]
// All angles are exact multiples of (r/4096) revolutions -> HW v_sin/v_cos.
// Two kernels: A computes per-(b,i,chunk) partial Fourier sums (128 blocks,
// no atomics, no zero-init of ws needed); B sums partials, mixes, writes.

#define KB   4
#define COUT 64
#define CIN  8
#define NN   4096
#define NCHUNK 4                     // t-chunks per (b,i) row
#define INV_N   (1.0f / 4096.0f)
#define INV_2PI 0.15915494309189535f

// ---------------- Kernel A: partial Fourier sums ----------------
// grid: KB*CIN*NCHUNK = 128 blocks, 256 threads.
// Fp[blk*4 + {cr,sr,ci,si}] -> d_ws  (128*4 floats)
__global__ __launch_bounds__(256) void f_partial_kernel(
    const float* __restrict__ zr,
    const float* __restrict__ zi,
    const int* __restrict__ m_ptr,
    float* __restrict__ Fp) {

    const int blk = blockIdx.x;              // pair*NCHUNK + chunk
    const int pair = blk >> 2, chunk = blk & (NCHUNK - 1);
    const int tid = threadIdx.x;
    const int m = *m_ptr;

    const float4* xr = (const float4*)(zr + pair * NN) + chunk * 256;
    const float4* xi = (const float4*)(zi + pair * NN) + chunk * 256;
    float4 vr = xr[tid];
    float4 vi = xi[tid];

    const int t0 = (chunk * 256 + tid) * 4;
    float fcr = 0.f, fsr = 0.f, fci = 0.f, fsi = 0.f;
    #pragma unroll
    for (int j = 0; j < 4; ++j) {
        int r = (m * (t0 + j)) & (NN - 1);   // exact phase mod 1 revolution
        float rev = (float)r * INV_N;
        float s = __builtin_amdgcn_sinf(rev);
        float c = __builtin_amdgcn_cosf(rev);
        float a = (&vr.x)[j], b = (&vi.x)[j];
        fcr += a * c;  fsr += a * s;
        fci += b * c;  fsi += b * s;
    }
    #pragma unroll
    for (int off = 32; off > 0; off >>= 1) {
        fcr += __shfl_down(fcr, off);
        fsr += __shfl_down(fsr, off);
        fci += __shfl_down(fci, off);
        fsi += __shfl_down(fsi, off);
    }
    __shared__ float red[4][4];
    int wave = tid >> 6, lane = tid & 63;
    if (lane == 0) {
        red[wave][0] = fcr; red[wave][1] = fsr;
        red[wave][2] = fci; red[wave][3] = fsi;
    }
    __syncthreads();
    if (tid == 0) {
        Fp[blk * 4 + 0] = red[0][0] + red[1][0] + red[2][0] + red[3][0];
        Fp[blk * 4 + 1] = red[0][1] + red[1][1] + red[2][1] + red[3][1];
        Fp[blk * 4 + 2] = red[0][2] + red[1][2] + red[2][2] + red[3][2];
        Fp[blk * 4 + 3] = red[0][3] + red[1][3] + red[2][3] + red[3][3];
    }
}

// ---------------- Kernel B: mix + gate + write ----------------
// grid: KB*COUT = 256 blocks, 256 threads; each block one (b,o) row.
__global__ __launch_bounds__(256) void out_kernel(
    const float* __restrict__ A,
    const float* __restrict__ beta,
    const float* __restrict__ bias,
    const int* __restrict__ m_ptr,
    const float* __restrict__ Fp,
    float* __restrict__ out) {

    const int blk = blockIdx.x;              // b*COUT + o
    const int b = blk >> 6, o = blk & (COUT - 1);
    const int m = *m_ptr;

    float Gr = 0.f, Hr = 0.f;
    #pragma unroll
    for (int i = 0; i < CIN; ++i) {
        float a  = fabsf(A[o * CIN + i]);
        float rb = beta[o * CIN + i] * INV_2PI;   // radians -> revolutions
        float cb = __builtin_amdgcn_cosf(rb);
        float sb = __builtin_amdgcn_sinf(rb);
        float P = a * cb, Q = a * sb;
        const float* f = Fp + (b * CIN + i) * NCHUNK * 4;
        float Fcr = 0.f, Fsr = 0.f, Fci = 0.f, Fsi = 0.f;
        #pragma unroll
        for (int ch = 0; ch < NCHUNK; ++ch) {
            Fcr += f[ch * 4 + 0];
            Fsr += f[ch * 4 + 1];
            Fci += f[ch * 4 + 2];
            Fsi += f[ch * 4 + 3];
        }
        Gr += -P * Fcr + Q * Fsr + Q * Fci + P * Fsi;
        Hr += -P * Fsr - Q * Fcr + Q * Fsi - P * Fci;
    }

    const float bo = bias[o];
    float4* out_r = (float4*)(out + ((long)blk << 12));
    float4* out_i = (float4*)(out + (long)KB * COUT * NN + ((long)blk << 12));

    #pragma unroll
    for (int k = 0; k < NN / 4 / 256; ++k) {     // 4 iters
        int vidx = threadIdx.x + k * 256;
        int mu0 = vidx * 4;
        float4 o1, o2;
        #pragma unroll
        for (int j = 0; j < 4; ++j) {
            int r = (m * (mu0 + j)) & (NN - 1);
            float rev = (float)r * INV_N;
            float s = __builtin_amdgcn_sinf(rev);
            float c = __builtin_amdgcn_cosf(rev);
            float sr = -(c * Gr + s * Hr);
            float si = s * Gr - c * Hr;          // Gi==Hr, Hi==-Gr (exact)
            float mag = sqrtf(sr * sr + si * si);
            float gate = 1.0f / ((1.0f + __expf(-(mag + bo))) * (mag + 1e-5f));
            (&o1.x)[j] = gate * sr;
            (&o2.x)[j] = gate * si;
        }
        out_r[vidx] = o1;
        out_i[vidx] = o2;
    }
}

extern "C" void kernel_launch(void* const* d_in, const int* in_sizes, int n_in,
                              void* d_out, int out_size, void* d_ws, size_t ws_size,
                              hipStream_t stream) {
    const float* z_real = (const float*)d_in[0];
    const float* z_imag = (const float*)d_in[1];
    const float* A      = (const float*)d_in[2];
    const float* beta   = (const float*)d_in[3];
    const float* bias   = (const float*)d_in[4];
    const int*   m_ptr  = (const int*)d_in[5];
    float* out = (float*)d_out;
    float* Fp  = (float*)d_ws;   // 128*4 floats of partial sums

    f_partial_kernel<<<KB * CIN * NCHUNK, 256, 0, stream>>>(z_real, z_imag, m_ptr, Fp);
    out_kernel<<<KB * COUT, 256, 0, stream>>>(A, beta, bias, m_ptr, Fp, out);
}